// Round 1
// baseline (46.477 us; speedup 1.0000x reference)
//
#include <hip/hip_runtime.h>
#include <math.h>

#define TEMP 5.0f
#define BIAS 0.0001f

// -------- Kernel 1: per-node dots s1[n]=ne[n].W[0:128], s2[n]=ne[n].W[128:256]
// One 64-lane wave per node; lane i loads float2 (elements 2i,2i+1) -> coalesced.
__global__ void node_dots_kernel(const float* __restrict__ ne,
                                 const float* __restrict__ W,
                                 float* __restrict__ s1,
                                 float* __restrict__ s2,
                                 int n_nodes) {
    const int lane   = threadIdx.x & 63;
    const int wid    = (blockIdx.x * blockDim.x + threadIdx.x) >> 6;
    const int nwaves = (gridDim.x * blockDim.x) >> 6;

    const float2* W2 = (const float2*)W;
    const float2 w1 = W2[lane];        // W[2i], W[2i+1]         (slice 0:128)
    const float2 w2 = W2[64 + lane];   // W[128+2i], W[128+2i+1] (slice 128:256)

    for (int node = wid; node < n_nodes; node += nwaves) {
        const float2 e = ((const float2*)(ne + (size_t)node * 128))[lane];
        float p1 = e.x * w1.x + e.y * w1.y;
        float p2 = e.x * w2.x + e.y * w2.y;
        #pragma unroll
        for (int off = 32; off; off >>= 1) {
            p1 += __shfl_xor(p1, off);
            p2 += __shfl_xor(p2, off);
        }
        if (lane == 0) {
            s1[node] = p1;
            s2[node] = p2;
        }
    }
}

// -------- Kernel 2: small tables
//   srel[r] = R[r] . W[256:384]                       (r < num_rel)
//   shq[b]  = ne[h_index[b]] . W[384:512]
//           + R[r_index[b]]  . W[512:640] + bias      (b < B)
__global__ void table_dots_kernel(const float* __restrict__ ne,
                                  const float* __restrict__ R,
                                  const float* __restrict__ W,
                                  const float* __restrict__ bias_ptr,
                                  const int* __restrict__ h_index,
                                  const int* __restrict__ r_index,
                                  float* __restrict__ srel,
                                  float* __restrict__ shq,
                                  int num_rel, int B) {
    const int lane   = threadIdx.x & 63;
    const int wid    = (blockIdx.x * blockDim.x + threadIdx.x) >> 6;
    const int nwaves = (gridDim.x * blockDim.x) >> 6;
    const int total  = num_rel + B;
    const float2* W2 = (const float2*)W;

    for (int t = wid; t < total; t += nwaves) {
        float p;
        if (t < num_rel) {
            const float2 w3 = W2[128 + lane];  // W[256:384]
            const float2 e  = ((const float2*)(R + (size_t)t * 128))[lane];
            p = e.x * w3.x + e.y * w3.y;
        } else {
            const int bb = t - num_rel;
            const float2 w4 = W2[192 + lane];  // W[384:512]
            const float2 w5 = W2[256 + lane];  // W[512:640]
            const float2 h  = ((const float2*)(ne + (size_t)h_index[bb] * 128))[lane];
            const float2 q  = ((const float2*)(R  + (size_t)r_index[bb] * 128))[lane];
            p = h.x * w4.x + h.y * w4.y + q.x * w5.x + q.y * w5.y;
        }
        #pragma unroll
        for (int off = 32; off; off >>= 1) p += __shfl_xor(p, off);
        if (lane == 0) {
            if (t < num_rel) srel[t] = p;
            else             shq[t - num_rel] = p + bias_ptr[0];
        }
    }
}

// -------- Kernel 3: per-edge gate
__global__ void edge_gate_kernel(const int* __restrict__ rows,
                                 const int* __restrict__ cols,
                                 const int* __restrict__ etype,
                                 const int* __restrict__ bid,
                                 const float* __restrict__ eps_u,
                                 const float* __restrict__ s1,
                                 const float* __restrict__ s2,
                                 const float* __restrict__ srel,
                                 const float* __restrict__ shq,
                                 float* __restrict__ out,
                                 int E) {
    int i = blockIdx.x * blockDim.x + threadIdx.x;
    const int stride = gridDim.x * blockDim.x;
    for (; i < E; i += stride) {
        const float sw = s1[rows[i]] + s2[cols[i]] + srel[etype[i]] + shq[bid[i]];
        const float u   = eps_u[i];
        const float eps = fmaf(u, (2.0f * BIAS - 1.0f), (1.0f - BIAS));
        const float logit = logf(eps) - log1pf(-eps);
        const float gate  = (logit + sw) * (1.0f / TEMP);
        out[i] = 1.0f / (1.0f + __expf(-gate));
    }
}

extern "C" void kernel_launch(void* const* d_in, const int* in_sizes, int n_in,
                              void* d_out, int out_size, void* d_ws, size_t ws_size,
                              hipStream_t stream) {
    const float* node_embeds = (const float*)d_in[0];
    const float* R           = (const float*)d_in[1];
    const float* W           = (const float*)d_in[2];
    const float* b           = (const float*)d_in[3];
    const float* eps_u       = (const float*)d_in[4];
    const int*   edge_index  = (const int*)d_in[5];
    const int*   edge_type   = (const int*)d_in[6];
    const int*   batch_id    = (const int*)d_in[7];
    const int*   h_index     = (const int*)d_in[8];
    const int*   r_index     = (const int*)d_in[9];

    const int D       = 128;
    const int n_nodes = in_sizes[0] / D;      // 200000
    const int num_rel = in_sizes[1] / D;      // 200
    const int E       = in_sizes[4];          // 500000
    const int B       = in_sizes[8];          // 256

    const int* rows = edge_index;
    const int* cols = edge_index + E;

    // workspace layout: s1[N] | s2[N] | srel[num_rel] | shq[B]
    float* s1   = (float*)d_ws;
    float* s2   = s1 + n_nodes;
    float* srel = s2 + n_nodes;
    float* shq  = srel + num_rel;

    // Kernel 1: one wave/node, grid-stride over nodes
    {
        const int block = 256;
        int grid = 2048;  // 8192 waves
        hipLaunchKernelGGL(node_dots_kernel, dim3(grid), dim3(block), 0, stream,
                           node_embeds, W, s1, s2, n_nodes);
    }

    // Kernel 2: one wave/table row (num_rel + B rows)
    {
        const int block = 256;
        const int total_waves = num_rel + B;
        int grid = (total_waves * 64 + block - 1) / block;
        hipLaunchKernelGGL(table_dots_kernel, dim3(grid), dim3(block), 0, stream,
                           node_embeds, R, W, b, h_index, r_index,
                           srel, shq, num_rel, B);
    }

    // Kernel 3: per-edge
    {
        const int block = 256;
        int grid = (E + block - 1) / block;
        if (grid > 4096) grid = 4096;
        hipLaunchKernelGGL(edge_gate_kernel, dim3(grid), dim3(block), 0, stream,
                           rows, cols, edge_type, batch_id, eps_u,
                           s1, s2, srel, shq, (float*)d_out, E);
    }
}

// Round 2
// 30.918 us; speedup vs baseline: 1.5032x; 1.5032x over previous
//
#include <hip/hip_runtime.h>
#include <math.h>

#define TEMP_INV 0.2f
#define BIAS 0.0001f

// -------- Kernel 1 (fused): node dots + rel table + head/query table
// Item space: [0, npairs) -> node pairs (2 nodes per wave, float4 loads)
//             [npairs, npairs+num_rel) -> srel rows
//             [.., +B) -> shq rows
__global__ void fused_dots_kernel(const float* __restrict__ ne,
                                  const float* __restrict__ R,
                                  const float* __restrict__ W,
                                  const float* __restrict__ bias_ptr,
                                  const int* __restrict__ h_index,
                                  const int* __restrict__ r_index,
                                  float* __restrict__ s1,
                                  float* __restrict__ s2,
                                  float* __restrict__ srel,
                                  float* __restrict__ shq,
                                  int n_nodes, int num_rel, int B) {
    const int lane   = threadIdx.x & 63;
    const int l32    = lane & 31;
    const int half   = lane >> 5;                       // 0 or 1: which node of the pair
    const int wid    = (blockIdx.x * blockDim.x + threadIdx.x) >> 6;
    const int nwaves = (gridDim.x * blockDim.x) >> 6;

    const int npairs = (n_nodes + 1) >> 1;
    const int total  = npairs + num_rel + B;

    const float4* W4 = (const float4*)W;
    const float4 w1 = W4[l32];        // W[0:128], lanes 0-31 cover the row
    const float4 w2 = W4[32 + l32];   // W[128:256]

    for (int t = wid; t < total; t += nwaves) {
        if (t < npairs) {
            const int node = 2 * t + half;
            float4 e = make_float4(0.f, 0.f, 0.f, 0.f);
            if (node < n_nodes)
                e = ((const float4*)(ne + (size_t)node * 128))[l32];
            float p1 = e.x * w1.x + e.y * w1.y + e.z * w1.z + e.w * w1.w;
            float p2 = e.x * w2.x + e.y * w2.y + e.z * w2.z + e.w * w2.w;
            // butterfly within each 32-lane half (offsets < 32 never cross halves)
            #pragma unroll
            for (int off = 16; off; off >>= 1) {
                p1 += __shfl_xor(p1, off);
                p2 += __shfl_xor(p2, off);
            }
            if (l32 == 0 && node < n_nodes) {
                s1[node] = p1;
                s2[node] = p2;
            }
        } else if (t < npairs + num_rel) {
            const int r = t - npairs;
            const float2* W2 = (const float2*)W;
            const float2 w3 = W2[128 + lane];  // W[256:384]
            const float2 e  = ((const float2*)(R + (size_t)r * 128))[lane];
            float p = e.x * w3.x + e.y * w3.y;
            #pragma unroll
            for (int off = 32; off; off >>= 1) p += __shfl_xor(p, off);
            if (lane == 0) srel[r] = p;
        } else {
            const int bb = t - npairs - num_rel;
            const float2* W2 = (const float2*)W;
            const float2 w4 = W2[192 + lane];  // W[384:512]
            const float2 w5 = W2[256 + lane];  // W[512:640]
            const float2 h  = ((const float2*)(ne + (size_t)h_index[bb] * 128))[lane];
            const float2 q  = ((const float2*)(R  + (size_t)r_index[bb] * 128))[lane];
            float p = h.x * w4.x + h.y * w4.y + q.x * w5.x + q.y * w5.y;
            #pragma unroll
            for (int off = 32; off; off >>= 1) p += __shfl_xor(p, off);
            if (lane == 0) shq[bb] = p + bias_ptr[0];
        }
    }
}

// -------- Kernel 2: per-edge gate, 4 edges/thread, vectorized streams
__device__ __forceinline__ float gate_one(float u, float sw) {
    const float eps   = fmaf(u, (2.0f * BIAS - 1.0f), (1.0f - BIAS));
    const float logit = __logf(eps) - __logf(1.0f - eps);
    const float g     = (logit + sw) * TEMP_INV;
    return __builtin_amdgcn_rcpf(1.0f + __expf(-g));
}

__global__ void edge_gate_kernel(const int* __restrict__ rows,
                                 const int* __restrict__ cols,
                                 const int* __restrict__ etype,
                                 const int* __restrict__ bid,
                                 const float* __restrict__ eps_u,
                                 const float* __restrict__ s1,
                                 const float* __restrict__ s2,
                                 const float* __restrict__ srel,
                                 const float* __restrict__ shq,
                                 float* __restrict__ out,
                                 int E) {
    const int tid = blockIdx.x * blockDim.x + threadIdx.x;
    const int i0  = tid * 4;
    if (i0 + 3 < E) {
        const int4   r4 = ((const int4*)rows)[tid];
        const int4   c4 = ((const int4*)cols)[tid];
        const int4   t4 = ((const int4*)etype)[tid];
        const int4   b4 = ((const int4*)bid)[tid];
        const float4 u4 = ((const float4*)eps_u)[tid];
        // issue all 16 gathers before consuming (MLP)
        const float a0 = s1[r4.x], a1 = s1[r4.y], a2 = s1[r4.z], a3 = s1[r4.w];
        const float c0 = s2[c4.x], c1 = s2[c4.y], c2 = s2[c4.z], c3 = s2[c4.w];
        const float e0 = srel[t4.x], e1 = srel[t4.y], e2 = srel[t4.z], e3 = srel[t4.w];
        const float q0 = shq[b4.x], q1 = shq[b4.y], q2 = shq[b4.z], q3 = shq[b4.w];
        float4 o;
        o.x = gate_one(u4.x, a0 + c0 + e0 + q0);
        o.y = gate_one(u4.y, a1 + c1 + e1 + q1);
        o.z = gate_one(u4.z, a2 + c2 + e2 + q2);
        o.w = gate_one(u4.w, a3 + c3 + e3 + q3);
        ((float4*)out)[tid] = o;
    } else if (i0 < E) {
        for (int i = i0; i < E; ++i) {
            const float sw = s1[rows[i]] + s2[cols[i]] + srel[etype[i]] + shq[bid[i]];
            out[i] = gate_one(eps_u[i], sw);
        }
    }
}

extern "C" void kernel_launch(void* const* d_in, const int* in_sizes, int n_in,
                              void* d_out, int out_size, void* d_ws, size_t ws_size,
                              hipStream_t stream) {
    const float* node_embeds = (const float*)d_in[0];
    const float* R           = (const float*)d_in[1];
    const float* W           = (const float*)d_in[2];
    const float* b           = (const float*)d_in[3];
    const float* eps_u       = (const float*)d_in[4];
    const int*   edge_index  = (const int*)d_in[5];
    const int*   edge_type   = (const int*)d_in[6];
    const int*   batch_id    = (const int*)d_in[7];
    const int*   h_index     = (const int*)d_in[8];
    const int*   r_index     = (const int*)d_in[9];

    const int D       = 128;
    const int n_nodes = in_sizes[0] / D;      // 200000
    const int num_rel = in_sizes[1] / D;      // 200
    const int E       = in_sizes[4];          // 500000
    const int B       = in_sizes[8];          // 256

    const int* rows = edge_index;
    const int* cols = edge_index + E;

    // workspace layout: s1[N] | s2[N] | srel[num_rel] | shq[B]
    float* s1   = (float*)d_ws;
    float* s2   = s1 + n_nodes;
    float* srel = s2 + n_nodes;
    float* shq  = srel + num_rel;

    // Kernel 1: fused dots. 2048 blocks x 4 waves = 8192 waves (32/CU cap).
    hipLaunchKernelGGL(fused_dots_kernel, dim3(2048), dim3(256), 0, stream,
                       node_embeds, R, W, b, h_index, r_index,
                       s1, s2, srel, shq, n_nodes, num_rel, B);

    // Kernel 2: per-edge, 4 edges/thread
    {
        const int threads = (E + 3) / 4;
        const int grid = (threads + 255) / 256;
        hipLaunchKernelGGL(edge_gate_kernel, dim3(grid), dim3(256), 0, stream,
                           rows, cols, edge_type, batch_id, eps_u,
                           s1, s2, srel, shq, (float*)d_out, E);
    }
}

// Round 3
// 30.694 us; speedup vs baseline: 1.5142x; 1.0073x over previous
//
#include <hip/hip_runtime.h>
#include <math.h>

#define TEMP_INV 0.2f
#define BIAS 0.0001f

// -------- Kernel 1 (fused): node dots + rel table + head/query table
// Super-item space: [0, supers) -> groups of 4 node-pairs (8 nodes, 4KB, loads
//                    issued up-front for MLP)
//                   [supers, supers+num_rel) -> srel rows
//                   [.., +B) -> shq rows
__global__ void fused_dots_kernel(const float* __restrict__ ne,
                                  const float* __restrict__ R,
                                  const float* __restrict__ W,
                                  const float* __restrict__ bias_ptr,
                                  const int* __restrict__ h_index,
                                  const int* __restrict__ r_index,
                                  float* __restrict__ s1,
                                  float* __restrict__ s2,
                                  float* __restrict__ srel,
                                  float* __restrict__ shq,
                                  int n_nodes, int num_rel, int B) {
    const int lane   = threadIdx.x & 63;
    const int l32    = lane & 31;
    const int half   = lane >> 5;                 // which node of the pair
    const int wid    = (blockIdx.x * blockDim.x + threadIdx.x) >> 6;
    const int nwaves = (gridDim.x * blockDim.x) >> 6;

    const int npairs = (n_nodes + 1) >> 1;
    const int supers = (npairs + 3) >> 2;
    const int total  = supers + num_rel + B;

    const float4* W4 = (const float4*)W;
    const float4 w1 = W4[l32];        // W[0:128]
    const float4 w2 = W4[32 + l32];   // W[128:256]

    for (int t = wid; t < total; t += nwaves) {
        if (t < supers) {
            const int pair0 = t * 4;
            float4 e[4];
            int node[4];
            // issue all 4 loads (4KB contiguous per wave) before any reduce
            #pragma unroll
            for (int j = 0; j < 4; ++j) {
                node[j] = (pair0 + j) * 2 + half;
                e[j] = make_float4(0.f, 0.f, 0.f, 0.f);
                if (node[j] < n_nodes)
                    e[j] = ((const float4*)(ne + (size_t)node[j] * 128))[l32];
            }
            #pragma unroll
            for (int j = 0; j < 4; ++j) {
                const float p1 = e[j].x * w1.x + e[j].y * w1.y + e[j].z * w1.z + e[j].w * w1.w;
                const float p2 = e[j].x * w2.x + e[j].y * w2.y + e[j].z * w2.z + e[j].w * w2.w;
                // fold: halves 0-15 reduce p1-sum, 16-31 reduce p2-sum
                const float q1 = __shfl_xor(p1, 16);
                const float q2 = __shfl_xor(p2, 16);
                float a = (l32 < 16) ? (p1 + q1) : (p2 + q2);
                a += __shfl_xor(a, 8);
                a += __shfl_xor(a, 4);
                a += __shfl_xor(a, 2);
                a += __shfl_xor(a, 1);
                if (node[j] < n_nodes) {
                    if (l32 == 0)       s1[node[j]] = a;
                    else if (l32 == 16) s2[node[j]] = a;
                }
            }
        } else if (t < supers + num_rel) {
            const int r = t - supers;
            const float2* W2 = (const float2*)W;
            const float2 w3 = W2[128 + lane];  // W[256:384]
            const float2 e  = ((const float2*)(R + (size_t)r * 128))[lane];
            float p = e.x * w3.x + e.y * w3.y;
            #pragma unroll
            for (int off = 32; off; off >>= 1) p += __shfl_xor(p, off);
            if (lane == 0) srel[r] = p;
        } else {
            const int bb = t - supers - num_rel;
            const float2* W2 = (const float2*)W;
            const float2 w4 = W2[192 + lane];  // W[384:512]
            const float2 w5 = W2[256 + lane];  // W[512:640]
            const float2 h  = ((const float2*)(ne + (size_t)h_index[bb] * 128))[lane];
            const float2 q  = ((const float2*)(R  + (size_t)r_index[bb] * 128))[lane];
            float p = h.x * w4.x + h.y * w4.y + q.x * w5.x + q.y * w5.y;
            #pragma unroll
            for (int off = 32; off; off >>= 1) p += __shfl_xor(p, off);
            if (lane == 0) shq[bb] = p + bias_ptr[0];
        }
    }
}

// -------- Kernel 2: per-edge gate, 2 edges/thread (15 waves/CU for latency hiding)
__device__ __forceinline__ float gate_one(float u, float sw) {
    const float eps   = fmaf(u, (2.0f * BIAS - 1.0f), (1.0f - BIAS));
    const float logit = __logf(eps) - __logf(1.0f - eps);
    const float g     = (logit + sw) * TEMP_INV;
    return __builtin_amdgcn_rcpf(1.0f + __expf(-g));
}

__global__ void edge_gate_kernel(const int* __restrict__ rows,
                                 const int* __restrict__ cols,
                                 const int* __restrict__ etype,
                                 const int* __restrict__ bid,
                                 const float* __restrict__ eps_u,
                                 const float* __restrict__ s1,
                                 const float* __restrict__ s2,
                                 const float* __restrict__ srel,
                                 const float* __restrict__ shq,
                                 float* __restrict__ out,
                                 int E) {
    const int tid = blockIdx.x * blockDim.x + threadIdx.x;
    const int i0  = tid * 2;
    if (i0 + 1 < E) {
        const int2   r2 = ((const int2*)rows)[tid];
        const int2   c2 = ((const int2*)cols)[tid];
        const int2   t2 = ((const int2*)etype)[tid];
        const int2   b2 = ((const int2*)bid)[tid];
        const float2 u2 = ((const float2*)eps_u)[tid];
        const float a0 = s1[r2.x],  a1 = s1[r2.y];
        const float c0 = s2[c2.x],  c1 = s2[c2.y];
        const float e0 = srel[t2.x], e1 = srel[t2.y];
        const float q0 = shq[b2.x], q1 = shq[b2.y];
        float2 o;
        o.x = gate_one(u2.x, a0 + c0 + e0 + q0);
        o.y = gate_one(u2.y, a1 + c1 + e1 + q1);
        ((float2*)out)[tid] = o;
    } else if (i0 < E) {
        const float sw = s1[rows[i0]] + s2[cols[i0]] + srel[etype[i0]] + shq[bid[i0]];
        out[i0] = gate_one(eps_u[i0], sw);
    }
}

extern "C" void kernel_launch(void* const* d_in, const int* in_sizes, int n_in,
                              void* d_out, int out_size, void* d_ws, size_t ws_size,
                              hipStream_t stream) {
    const float* node_embeds = (const float*)d_in[0];
    const float* R           = (const float*)d_in[1];
    const float* W           = (const float*)d_in[2];
    const float* b           = (const float*)d_in[3];
    const float* eps_u       = (const float*)d_in[4];
    const int*   edge_index  = (const int*)d_in[5];
    const int*   edge_type   = (const int*)d_in[6];
    const int*   batch_id    = (const int*)d_in[7];
    const int*   h_index     = (const int*)d_in[8];
    const int*   r_index     = (const int*)d_in[9];

    const int D       = 128;
    const int n_nodes = in_sizes[0] / D;      // 200000
    const int num_rel = in_sizes[1] / D;      // 200
    const int E       = in_sizes[4];          // 500000
    const int B       = in_sizes[8];          // 256

    const int* rows = edge_index;
    const int* cols = edge_index + E;

    // workspace layout: s1[N] | s2[N] | srel[num_rel] | shq[B]
    float* s1   = (float*)d_ws;
    float* s2   = s1 + n_nodes;
    float* srel = s2 + n_nodes;
    float* shq  = srel + num_rel;

    // Kernel 1: fused dots. 2048 blocks x 4 waves = 8192 waves (32/CU cap).
    hipLaunchKernelGGL(fused_dots_kernel, dim3(2048), dim3(256), 0, stream,
                       node_embeds, R, W, b, h_index, r_index,
                       s1, s2, srel, shq, n_nodes, num_rel, B);

    // Kernel 2: per-edge, 2 edges/thread -> 977 blocks (~15 waves/CU)
    {
        const int threads = (E + 1) / 2;
        const int grid = (threads + 255) / 256;
        hipLaunchKernelGGL(edge_gate_kernel, dim3(grid), dim3(256), 0, stream,
                           rows, cols, edge_type, batch_id, eps_u,
                           s1, s2, srel, shq, (float*)d_out, E);
    }
}